// Round 6
// baseline (191.790 us; speedup 1.0000x reference)
//
#include <hip/hip_runtime.h>

#define N_NODES 200000
#define N_EDGES 600000
#define F_IN 165
#define F_HID 128
#define KP 200     // row stride (ushorts) for wt
#define NRT 12500  // 200000/16 row-tiles

typedef short short8 __attribute__((ext_vector_type(8)));
typedef float f32x4 __attribute__((ext_vector_type(4)));

__device__ __forceinline__ unsigned short f2bf(float f) {
  union { float f; unsigned int u; } v; v.f = f;
  unsigned int u = v.u;
  return (unsigned short)((u + 0x7FFFu + ((u >> 16) & 1u)) >> 16);  // RNE
}
__device__ __forceinline__ float bflo(unsigned int v) {
  union { unsigned int u; float f; } x; x.u = v << 16; return x.f;
}
__device__ __forceinline__ float bfhi(unsigned int v) {
  union { unsigned int u; float f; } x; x.u = v & 0xffff0000u; return x.f;
}

// ---- zero scratch counters + build W1^T bf16 [128][KP] (fused; graph-replayed) ----
__global__ void k_zero(int* __restrict__ cnt, const float* __restrict__ W1,
                       unsigned short* __restrict__ wt) {
  int i = blockIdx.x * 256 + threadIdx.x;
  if (i < N_NODES) cnt[i] = 0;
  if (i < F_HID * KP) {
    int c = i / KP, k = i - c * KP;
    wt[i] = (k < F_IN) ? f2bf(W1[k * F_HID + c]) : (unsigned short)0;
  }
}

// ---- CSR build ----
__global__ void k_count(const int* __restrict__ ei, int* __restrict__ cnt) {
  int e = blockIdx.x * 256 + threadIdx.x;
  if (e < N_EDGES) atomicAdd(&cnt[ei[N_EDGES + e]], 1);
}

__global__ void k_scan1(const int* __restrict__ cnt, int* __restrict__ rowptr, int* __restrict__ bsum) {
  __shared__ int sd[256];
  int t = threadIdx.x;
  int idx = blockIdx.x * 256 + t;
  int v = (idx < N_NODES) ? cnt[idx] : 0;
  sd[t] = v; __syncthreads();
  #pragma unroll
  for (int off = 1; off < 256; off <<= 1) {
    int u = (t >= off) ? sd[t - off] : 0;
    __syncthreads();
    sd[t] += u;
    __syncthreads();
  }
  if (idx < N_NODES) rowptr[idx] = sd[t] - v;  // exclusive within block
  if (t == 255) bsum[blockIdx.x] = sd[t];
}

__global__ void k_scan2(int* __restrict__ bsum, int nb) {
  __shared__ int sd[1024];
  int t = threadIdx.x;
  int v = (t < nb) ? bsum[t] : 0;
  sd[t] = v; __syncthreads();
  for (int off = 1; off < 1024; off <<= 1) {
    int u = (t >= off) ? sd[t - off] : 0;
    __syncthreads();
    sd[t] += u;
    __syncthreads();
  }
  if (t < nb) bsum[t] = sd[t] - v;  // exclusive block offsets
}

__global__ void k_scan3(const int* __restrict__ cnt, const int* __restrict__ bsum,
                        int* __restrict__ rowptr, int* __restrict__ fill, float* __restrict__ dinv) {
  int idx = blockIdx.x * 256 + threadIdx.x;
  if (idx < N_NODES) {
    int rp = rowptr[idx] + bsum[blockIdx.x];
    rowptr[idx] = rp;
    fill[idx] = rp;  // mutable cursor for k_fill
    dinv[idx] = rsqrtf((float)(cnt[idx] + 1));  // deg = in-degree + self-loop >= 1
  }
  if (idx == 0) rowptr[N_NODES] = N_EDGES;
}

__global__ void k_fill(const int* __restrict__ ei, int* __restrict__ fill, int* __restrict__ srcl) {
  int e = blockIdx.x * 256 + threadIdx.x;
  if (e < N_EDGES) {
    int d = ei[N_EDGES + e];
    int s = ei[e];
    int slot = atomicAdd(&fill[d], 1);
    srcl[slot] = s;
  }
}

// ---- GEMM1: barrier-free, LDS-free. Wave-tile = 16 rows x 64 cols; W in VGPRs;
//      x fragments loaded directly from global (scalar dwords, rows 4B-aligned). ----
// wave: cw = gw&1 (col-half, wf reused across its whole tile stream), t strides row-tiles.
// acc[cb] = mfma(wf, xf): lane owns x-row t*16+(lane&15);
//   cols cw*64 + cb*16 + (lane>>4)*4 + j  -> packed dwordx2 stores (verified round 5).
__global__ __launch_bounds__(256) void k_gemm1(const float* __restrict__ x,
                                               const unsigned short* __restrict__ wt,
                                               const float* __restrict__ dinv,
                                               unsigned short* __restrict__ h16) {
  int tid = threadIdx.x;
  int lane = tid & 63;
  int gw = blockIdx.x * 4 + (tid >> 6);
  int nw = gridDim.x * 4;
  int cw = gw & 1;
  int lane15 = lane & 15;
  int kq = (lane >> 4) * 8;

  // hoist W fragments: 4 col-blocks x 6 k-steps (96 VGPRs), once per wave
  short8 wf[4][6];
  {
    int c0 = cw * 64 + lane15;
    #pragma unroll
    for (int cb = 0; cb < 4; ++cb) {
      #pragma unroll
      for (int ks = 0; ks < 6; ++ks) {
        wf[cb][ks] = *(const short8*)(&wt[(c0 + cb * 16) * KP + ks * 32 + kq]);
      }
    }
  }

  for (int t = gw >> 1; t < NRT; t += (nw >> 1)) {
    long r = (long)t * 16 + lane15;
    const float* xr = x + r * F_IN;

    // load + convert 6 x-fragments (8 consecutive floats each; ks=5 predicated past k=165)
    short8 xf[6];
    #pragma unroll
    for (int ks = 0; ks < 6; ++ks) {
      int k0 = ks * 32 + kq;
      short8 s;
      #pragma unroll
      for (int j = 0; j < 8; ++j) {
        float vv = (ks * 32 + 31 < F_IN) ? xr[k0 + j]
                 : ((k0 + j < F_IN) ? xr[k0 + j] : 0.f);
        s[j] = (short)f2bf(vv);
      }
      xf[ks] = s;
    }

    f32x4 acc[4];
    #pragma unroll
    for (int i = 0; i < 4; ++i) acc[i] = (f32x4){0.f, 0.f, 0.f, 0.f};
    #pragma unroll
    for (int ks = 0; ks < 6; ++ks) {
      #pragma unroll
      for (int cb = 0; cb < 4; ++cb) {
        acc[cb] = __builtin_amdgcn_mfma_f32_16x16x32_bf16(wf[cb][ks], xf[ks], acc[cb], 0, 0, 0);
      }
    }

    // epilogue: lane owns one row; scale by dinv, pack 4 bf16 -> 8B store per cb
    float dd = dinv[r];
    unsigned short* hp = &h16[r * F_HID + cw * 64 + (lane >> 4) * 4];
    #pragma unroll
    for (int cb = 0; cb < 4; ++cb) {
      unsigned int p0 = (unsigned int)f2bf(acc[cb][0] * dd) | ((unsigned int)f2bf(acc[cb][1] * dd) << 16);
      unsigned int p1 = (unsigned int)f2bf(acc[cb][2] * dd) | ((unsigned int)f2bf(acc[cb][3] * dd) << 16);
      uint2 pp; pp.x = p0; pp.y = p1;
      *(uint2*)(hp + cb * 16) = pp;
    }
  }
}

// ---- fused: agg1 (gather, 4-wide) + bias + relu + GEMM2 (128->2) ; output pre-scaled by dinv ----
__global__ __launch_bounds__(256) void k_agg1(const unsigned int* __restrict__ H,  // bf16x2 rows, 64 uints/node
                                              const float* __restrict__ dinv,
                                              const int* __restrict__ rowptr, const int* __restrict__ srcl,
                                              const float* __restrict__ b1, const float* __restrict__ W2,
                                              float* __restrict__ h2s) {
  int tid = threadIdx.x;
  int local = tid >> 6;
  int lane = tid & 63;
  int d = blockIdx.x * 4 + local;  // grid exact: 50000*4 = 200000

  unsigned int v = H[(long)d * 64 + lane];  // self (already dinv[d]-scaled)
  float acc0 = bflo(v), acc1 = bfhi(v);
  int r0 = rowptr[d], r1 = rowptr[d + 1];
  int n = r1 - r0;
  for (int b = 0; b < n; b += 4) {
    int i0 = r0 + b;
    bool m1 = b + 1 < n, m2 = b + 2 < n, m3 = b + 3 < n;
    int s0 = srcl[i0];
    int s1 = m1 ? srcl[i0 + 1] : s0;
    int s2 = m2 ? srcl[i0 + 2] : s0;
    int s3 = m3 ? srcl[i0 + 3] : s0;
    unsigned int v0 = H[(long)s0 * 64 + lane];
    unsigned int v1 = H[(long)s1 * 64 + lane];
    unsigned int v2 = H[(long)s2 * 64 + lane];
    unsigned int v3 = H[(long)s3 * 64 + lane];
    acc0 += bflo(v0);                      acc1 += bfhi(v0);
    acc0 = fmaf(m1 ? 1.f : 0.f, bflo(v1), acc0); acc1 = fmaf(m1 ? 1.f : 0.f, bfhi(v1), acc1);
    acc0 = fmaf(m2 ? 1.f : 0.f, bflo(v2), acc0); acc1 = fmaf(m2 ? 1.f : 0.f, bfhi(v2), acc1);
    acc0 = fmaf(m3 ? 1.f : 0.f, bflo(v3), acc0); acc1 = fmaf(m3 ? 1.f : 0.f, bfhi(v3), acc1);
  }
  float dd = dinv[d];
  float2 bb = ((const float2*)b1)[lane];
  float a0 = fmaxf(fmaf(acc0, dd, bb.x), 0.f);
  float a1 = fmaxf(fmaf(acc1, dd, bb.y), 0.f);
  float4 w2 = ((const float4*)W2)[lane];  // W2[2*lane][0..1], W2[2*lane+1][0..1]
  float p0 = a0 * w2.x + a1 * w2.z;
  float p1 = a0 * w2.y + a1 * w2.w;
  #pragma unroll
  for (int off = 32; off > 0; off >>= 1) {
    p0 += __shfl_down(p0, off);
    p1 += __shfl_down(p1, off);
  }
  if (lane == 0) ((float2*)h2s)[d] = make_float2(p0 * dd, p1 * dd);
}

// ---- agg2 over 2 features + bias (h2s pre-scaled by dinv) ----
__global__ void k_agg2(const float* __restrict__ h2s, const float* __restrict__ dinv,
                       const int* __restrict__ rowptr, const int* __restrict__ srcl,
                       const float* __restrict__ b2, float* __restrict__ out) {
  int d = blockIdx.x * 256 + threadIdx.x;
  if (d >= N_NODES) return;
  const float2* G = (const float2*)h2s;
  float2 g = G[d];
  float o0 = g.x, o1 = g.y;
  int r0 = rowptr[d], r1 = rowptr[d + 1];
  int n = r1 - r0;
  for (int b = 0; b < n; b += 4) {
    int i0 = r0 + b;
    bool m1 = b + 1 < n, m2 = b + 2 < n, m3 = b + 3 < n;
    int s0 = srcl[i0];
    int s1 = m1 ? srcl[i0 + 1] : s0;
    int s2 = m2 ? srcl[i0 + 2] : s0;
    int s3 = m3 ? srcl[i0 + 3] : s0;
    float2 g0 = G[s0], g1 = G[s1], g2 = G[s2], g3 = G[s3];
    o0 += g0.x;                   o1 += g0.y;
    o0 = fmaf(m1 ? 1.f : 0.f, g1.x, o0); o1 = fmaf(m1 ? 1.f : 0.f, g1.y, o1);
    o0 = fmaf(m2 ? 1.f : 0.f, g2.x, o0); o1 = fmaf(m2 ? 1.f : 0.f, g2.y, o1);
    o0 = fmaf(m3 ? 1.f : 0.f, g3.x, o0); o1 = fmaf(m3 ? 1.f : 0.f, g3.y, o1);
  }
  float dd = dinv[d];
  ((float2*)out)[d] = make_float2(fmaf(o0, dd, b2[0]), fmaf(o1, dd, b2[1]));
}

extern "C" void kernel_launch(void* const* d_in, const int* in_sizes, int n_in,
                              void* d_out, int out_size, void* d_ws, size_t ws_size,
                              hipStream_t stream) {
  const float* x  = (const float*)d_in[0];
  const int*   ei = (const int*)d_in[1];
  const float* W1 = (const float*)d_in[2];
  const float* b1 = (const float*)d_in[3];
  const float* W2 = (const float*)d_in[4];
  const float* b2 = (const float*)d_in[5];
  float* out = (float*)d_out;

  char* p = (char*)d_ws;
  size_t off = 0;
  auto take = [&](size_t bytes) -> void* {
    void* r = p + off;
    off += (bytes + 255) & ~(size_t)255;
    return r;
  };
  unsigned short* h16    = (unsigned short*)take((size_t)N_NODES * F_HID * 2);  // 51.2 MB, dinv-scaled bf16
  unsigned short* wt     = (unsigned short*)take((size_t)F_HID * KP * 2);
  float*          h2s    = (float*)take((size_t)N_NODES * 2 * 4);
  int*            cnt    = (int*)take((size_t)N_NODES * 4);
  int*            fill   = (int*)take((size_t)N_NODES * 4);
  int*            rowptr = (int*)take(((size_t)N_NODES + 1) * 4);
  int*            srcl   = (int*)take(((size_t)N_EDGES + 8) * 4);  // +8 pad for speculative unroll reads
  float*          dinv   = (float*)take((size_t)N_NODES * 4);
  int*            bsum   = (int*)take(4096);
  (void)ws_size; (void)in_sizes; (void)n_in; (void)out_size;

  int nbE = (N_EDGES + 255) / 256;
  int nbN = (N_NODES + 255) / 256;
  k_zero<<<nbN, 256, 0, stream>>>(cnt, W1, wt);
  k_count<<<nbE, 256, 0, stream>>>(ei, cnt);
  k_scan1<<<nbN, 256, 0, stream>>>(cnt, rowptr, bsum);
  k_scan2<<<1, 1024, 0, stream>>>(bsum, nbN);
  k_scan3<<<nbN, 256, 0, stream>>>(cnt, bsum, rowptr, fill, dinv);
  k_fill<<<nbE, 256, 0, stream>>>(ei, fill, srcl);
  k_gemm1<<<1024, 256, 0, stream>>>(x, wt, dinv, h16);  // barrier-free wave streams
  k_agg1<<<N_NODES / 4, 256, 0, stream>>>((const unsigned int*)h16, dinv, rowptr, srcl, b1, W2, h2s);
  k_agg2<<<nbN, 256, 0, stream>>>(h2s, dinv, rowptr, srcl, b2, out);
}